// Round 6
// baseline (586.727 us; speedup 1.0000x reference)
//
#include <hip/hip_runtime.h>
#include <hip/hip_bf16.h>

#define D 128
#define CAT 640
#define BM 32
#define G 4                // seed-groups per block (software pipeline depth)
#define W1F_ELEMS 81920    // 20*8*64*8
#define W2F_ELEMS 16384    // 4*8*64*8

typedef __attribute__((ext_vector_type(8))) short bf16x8;
typedef __attribute__((ext_vector_type(4))) short short4v;
typedef __attribute__((ext_vector_type(4))) float f32x4;

static __device__ __forceinline__ unsigned short f32_to_bf16(float f) {
    unsigned u = __float_as_uint(f);
    unsigned r = u + 0x7FFFu + ((u >> 16) & 1u);   // RNE
    return (unsigned short)(r >> 16);
}

// Pack W1 [128][640] and W2 [128][128] (fp32, torch Linear [out,in]) into MFMA
// B-fragment order: (ks, j16, lane, e) = W[j16*16 + (lane&15)][ks*32 + (lane>>4)*8 + e]
__global__ void prep_frags(const float* __restrict__ W1, const float* __restrict__ W2,
                           unsigned short* __restrict__ W1f, unsigned short* __restrict__ W2f) {
    int f = blockIdx.x * 256 + threadIdx.x;
    if (f < W1F_ELEMS) {
        int e = f & 7, l = (f >> 3) & 63, j16 = (f >> 9) & 7, ks = f >> 12;
        int o = j16 * 16 + (l & 15);
        int k = ks * 32 + ((l >> 4) << 3) + e;
        W1f[f] = f32_to_bf16(W1[o * CAT + k]);
    } else if (f < W1F_ELEMS + W2F_ELEMS) {
        int f2 = f - W1F_ELEMS;
        int e = f2 & 7, l = (f2 >> 3) & 63, j16 = (f2 >> 9) & 7, ks = f2 >> 12;
        int o = j16 * 16 + (l & 15);
        int k = ks * 32 + ((l >> 4) << 3) + e;
        W2f[f2] = f32_to_bf16(W2[o * D + k]);
    }
}

// R6: R1's block structure, but each block runs G=4 seed-groups with the
// gather for group g+1 issued into registers BEFORE group g's GEMMs and
// committed to LDS after — loads stay in flight during compute (T14 split),
// so HBM load issue is continuous instead of phase-gated.
// Staging in two 10-load halves keeps live staging VGPRs at 40.
__global__ __launch_bounds__(256, 3) void rowmlp_kernel(
    const float* __restrict__ x_rows, const int* __restrict__ seeds,
    const unsigned short* __restrict__ W1f, const float* __restrict__ b1,
    const unsigned short* __restrict__ W2f, const float* __restrict__ b2,
    float* __restrict__ out, int Nrows)
{
    __shared__ __align__(16) unsigned short Ab[BM][CAT];  // 40 KB, XOR-swizzled
    __shared__ __align__(16) unsigned short Hb[BM][D];    // 8 KB, XOR-swizzled
    __shared__ int sseed[G * BM];

    const int tid = threadIdx.x;
    const int blk = blockIdx.x;
    const int lane32  = tid & 31;
    const int segbase = tid >> 5;     // 0..7

    if (tid < G * BM) sseed[tid] = seeds[blk * (G * BM) + tid];
    __syncthreads();

    // issue 10 independent float4 gathers for half IT0 of group g (no waits)
#define ISSUE(ST, g, IT0)                                                      \
    _Pragma("unroll")                                                          \
    for (int it = 0; it < 10; ++it) {                                          \
        int seg = (it + IT0) * 8 + segbase;                                    \
        int row = seg / 5;                                                     \
        int j = seg - row * 5;                                                 \
        int idx = sseed[(g) * BM + row] + j - 2;                               \
        idx = idx < 0 ? 0 : (idx >= Nrows ? Nrows - 1 : idx);                  \
        ST[it] = *((const float4*)(x_rows + (size_t)idx * D) + lane32);        \
    }

    // convert staged half to bf16 and write into swizzled Ab (waits on loads)
#define COMMIT(ST, IT0)                                                        \
    _Pragma("unroll")                                                          \
    for (int it = 0; it < 10; ++it) {                                          \
        int seg = (it + IT0) * 8 + segbase;                                    \
        int row = seg / 5;                                                     \
        int j = seg - row * 5;                                                 \
        short4v p;                                                             \
        p[0] = (short)f32_to_bf16(ST[it].x); p[1] = (short)f32_to_bf16(ST[it].y); \
        p[2] = (short)f32_to_bf16(ST[it].z); p[3] = (short)f32_to_bf16(ST[it].w); \
        int kshort = j * D + lane32 * 4;                                       \
        *(short4v*)(&Ab[row][kshort ^ ((row & 7) << 3)]) = p;                  \
    }

    const int wave = tid >> 6;   // 0..3: N-column group
    const int l    = tid & 63;
    const int l15  = l & 15;
    const int lhi  = l >> 4;

    const bf16x8* W1v = (const bf16x8*)W1f;
    const bf16x8* W2v = (const bf16x8*)W2f;

    float4 st_a[10], st_b[10];

    // prologue: fill Ab for group 0
    ISSUE(st_a, 0, 0)
    ISSUE(st_b, 0, 10)
    COMMIT(st_a, 0)
    COMMIT(st_b, 10)
    __syncthreads();

    for (int g = 0; g < G; ++g) {
        // stage first half of next group's gather — in flight during GEMM1
        if (g < G - 1) ISSUE(st_a, g + 1, 0)

        // ---- GEMM1: h = x_cat @ W1^T  (M=32, N=32/wave, K=640)
        f32x4 acc[2][2] = {};
        #pragma unroll
        for (int ks = 0; ks < 20; ++ks) {
            bf16x8 a[2], b[2];
            #pragma unroll
            for (int m = 0; m < 2; ++m) {
                int row = m * 16 + l15;
                a[m] = *(const bf16x8*)(&Ab[row][(ks * 32 + lhi * 8) ^ ((row & 7) << 3)]);
            }
            #pragma unroll
            for (int n = 0; n < 2; ++n) {
                int j16 = wave * 2 + n;
                b[n] = W1v[(ks * 8 + j16) * 64 + l];
            }
            #pragma unroll
            for (int m = 0; m < 2; ++m)
                #pragma unroll
                for (int n = 0; n < 2; ++n)
                    acc[m][n] = __builtin_amdgcn_mfma_f32_16x16x32_bf16(a[m], b[n], acc[m][n], 0, 0, 0);
        }

        // ---- bias + ReLU -> bf16 h tile (swizzled)
        #pragma unroll
        for (int n = 0; n < 2; ++n) {
            int col = wave * 32 + n * 16 + l15;
            float bias = b1[col];
            #pragma unroll
            for (int m = 0; m < 2; ++m) {
                #pragma unroll
                for (int r = 0; r < 4; ++r) {
                    float v = acc[m][n][r] + bias;
                    v = v > 0.f ? v : 0.f;
                    int row = m * 16 + lhi * 4 + r;   // C/D: col=lane&15, row=(lane>>4)*4+reg
                    Hb[row][col ^ ((row & 7) << 3)] = f32_to_bf16(v);
                }
            }
        }
        __syncthreads();   // Hb ready; all waves done reading Ab

        // commit half A (rows 0..15) and stage half B — in flight during GEMM2
        if (g < G - 1) {
            COMMIT(st_a, 0)
            ISSUE(st_b, g + 1, 10)
        }

        // ---- GEMM2: out = h @ W2^T  (M=32, N=32/wave, K=128)
        f32x4 acc2[2][2] = {};
        #pragma unroll
        for (int ks = 0; ks < 4; ++ks) {
            bf16x8 a[2], b[2];
            #pragma unroll
            for (int m = 0; m < 2; ++m) {
                int row = m * 16 + l15;
                a[m] = *(const bf16x8*)(&Hb[row][(ks * 32 + lhi * 8) ^ ((row & 7) << 3)]);
            }
            #pragma unroll
            for (int n = 0; n < 2; ++n) {
                int j16 = wave * 2 + n;
                b[n] = W2v[(ks * 8 + j16) * 64 + l];
            }
            #pragma unroll
            for (int m = 0; m < 2; ++m)
                #pragma unroll
                for (int n = 0; n < 2; ++n)
                    acc2[m][n] = __builtin_amdgcn_mfma_f32_16x16x32_bf16(a[m], b[n], acc2[m][n], 0, 0, 0);
        }

        // ---- bias + fp32 store
        const size_t rowbase = (size_t)blk * (G * BM) + g * BM;
        #pragma unroll
        for (int n = 0; n < 2; ++n) {
            int col = wave * 32 + n * 16 + l15;
            float bias = b2[col];
            #pragma unroll
            for (int m = 0; m < 2; ++m) {
                #pragma unroll
                for (int r = 0; r < 4; ++r) {
                    int row = m * 16 + lhi * 4 + r;
                    out[(rowbase + row) * D + col] = acc2[m][n][r] + bias;
                }
            }
        }

        // commit half B (rows 16..31), then release Ab for next GEMM1
        if (g < G - 1) {
            COMMIT(st_b, 10)
            __syncthreads();
        }
    }
#undef ISSUE
#undef COMMIT
}

extern "C" void kernel_launch(void* const* d_in, const int* in_sizes, int n_in,
                              void* d_out, int out_size, void* d_ws, size_t ws_size,
                              hipStream_t stream) {
    const float* x_rows = (const float*)d_in[0];
    const int*   seeds  = (const int*)d_in[1];
    const float* W1     = (const float*)d_in[2];
    const float* b1     = (const float*)d_in[3];
    const float* W2     = (const float*)d_in[4];
    const float* b2     = (const float*)d_in[5];
    float* out = (float*)d_out;

    int Nrows = in_sizes[0] / D;
    int B = in_sizes[1];

    unsigned short* W1f = (unsigned short*)d_ws;
    unsigned short* W2f = W1f + W1F_ELEMS;

    prep_frags<<<(W1F_ELEMS + W2F_ELEMS + 255) / 256, 256, 0, stream>>>(W1, W2, W1f, W2f);
    rowmlp_kernel<<<B / (G * BM), 256, 0, stream>>>(x_rows, seeds, W1f, b1, W2f, b2, out, Nrows);
}

// Round 7
// 192.572 us; speedup vs baseline: 3.0468x; 3.0468x over previous
//
#include <hip/hip_runtime.h>
#include <hip/hip_bf16.h>

#define D 128
#define CAT 640
#define BM 32
#define W1F_ELEMS 81920    // 20*8*64*8
#define W2F_ELEMS 16384    // 4*8*64*8

typedef __attribute__((ext_vector_type(8))) short bf16x8;
typedef __attribute__((ext_vector_type(4))) float f32x4;

static __device__ __forceinline__ unsigned short f32_to_bf16(float f) {
    unsigned u = __float_as_uint(f);
    unsigned r = u + 0x7FFFu + ((u >> 16) & 1u);   // RNE
    return (unsigned short)(r >> 16);
}

static __device__ __forceinline__ unsigned pack_bf16x2(float a, float b) {
    __hip_bfloat162 h = __float22bfloat162_rn(make_float2(a, b));  // v_cvt_pk_bf16_f32
    return *reinterpret_cast<unsigned*>(&h);
}

// async global->LDS, 16B per lane, wave-uniform LDS base + lane*16
static __device__ __forceinline__ void gload_lds16(const float* g, void* lds) {
    __builtin_amdgcn_global_load_lds(
        (const __attribute__((address_space(1))) void*)g,
        (__attribute__((address_space(3))) void*)lds, 16, 0, 0);
}

// Pack W1 [128][640] and W2 [128][128] (fp32, torch Linear [out,in]) into MFMA
// B-fragment order: (ks, j16, lane, e) = W[j16*16 + (lane&15)][ks*32 + (lane>>4)*8 + e]
__global__ void prep_frags(const float* __restrict__ W1, const float* __restrict__ W2,
                           unsigned short* __restrict__ W1f, unsigned short* __restrict__ W2f) {
    int f = blockIdx.x * 256 + threadIdx.x;
    if (f < W1F_ELEMS) {
        int e = f & 7, l = (f >> 3) & 63, j16 = (f >> 9) & 7, ks = f >> 12;
        int o = j16 * 16 + (l & 15);
        int k = ks * 32 + ((l >> 4) << 3) + e;
        W1f[f] = f32_to_bf16(W1[o * CAT + k]);
    } else if (f < W1F_ELEMS + W2F_ELEMS) {
        int f2 = f - W1F_ELEMS;
        int e = f2 & 7, l = (f2 >> 3) & 63, j16 = (f2 >> 9) & 7, ks = f2 >> 12;
        int o = j16 * 16 + (l & 15);
        int k = ks * 32 + ((l >> 4) << 3) + e;
        W2f[f2] = f32_to_bf16(W2[o * D + k]);
    }
}

// R7: GEMM1's K=640 = 5 neighbor-chunks of 32 rows x 128 fp32 (16 KB),
// double-buffered in LDS via async global_load_lds (zero staging VGPRs).
// Per chunk: wait own loads -> s_barrier -> issue next chunk -> MFMA current.
// Loads stay in flight during compute on every wave (no phase-gating).
// Per-lane global addrs are pre-swizzled so linear LDS writes land XOR-swizzled.
// LDS 32.1 KB -> 4 blocks/CU = 16 waves/CU. Hb aliases buf[1] after GEMM1.
__global__ __launch_bounds__(256, 4) void rowmlp_kernel(
    const float* __restrict__ x_rows, const int* __restrict__ seeds,
    const unsigned short* __restrict__ W1f, const float* __restrict__ b1,
    const unsigned short* __restrict__ W2f, const float* __restrict__ b2,
    float* __restrict__ out, int Nrows)
{
    __shared__ __align__(16) unsigned char smem[2][16384];
    __shared__ int sseed[BM];

    const int tid = threadIdx.x;
    const int blk = blockIdx.x;

    if (tid < BM) sseed[tid] = seeds[blk * BM + tid];
    __syncthreads();

    const int w   = tid >> 6;    // wave id: stages rows 8w..8w+7; owns n-cols 32w..32w+31
    const int l   = tid & 63;
    const int l15 = l & 15;
    const int lhi = l >> 4;

    // staging geometry (fixed per thread): instr i covers rows 8w+2i, 8w+2i+1;
    // lane covers 16B chunk c=l&31 of its row; source chunk pre-swizzled c^(r&7).
    int sbase[4], scoff[4];
    #pragma unroll
    for (int i = 0; i < 4; ++i) {
        int r = 8 * w + 2 * i + (l >> 5);
        sbase[i] = sseed[r];
        scoff[i] = ((l & 31) ^ (r & 7)) << 2;   // float offset within row
    }

#define ISSUE(J)                                                               \
    {                                                                          \
        _Pragma("unroll")                                                      \
        for (int i = 0; i < 4; ++i) {                                          \
            int idx = sbase[i] + (J) - 2;                                      \
            idx = idx < 0 ? 0 : (idx >= Nrows ? Nrows - 1 : idx);              \
            gload_lds16(x_rows + (size_t)idx * D + scoff[i],                   \
                        (void*)(smem[(J) & 1] + w * 4096 + i * 1024));         \
        }                                                                      \
    }

    ISSUE(0)

    const bf16x8* W1v = (const bf16x8*)W1f;
    const bf16x8* W2v = (const bf16x8*)W2f;

    f32x4 acc[2][2] = {};

    #pragma unroll
    for (int j = 0; j < 5; ++j) {
        // own chunk-j loads done -> barrier -> everyone's chunk-j visible,
        // and everyone finished reading buf[(j-1)&1] (compute j-1 precedes this).
        asm volatile("s_waitcnt vmcnt(0)" ::: "memory");
        __builtin_amdgcn_s_barrier();
        if (j < 4) ISSUE(j + 1)           // in flight during compute j

        const float* buf = (const float*)smem[j & 1];
        #pragma unroll
        for (int ks = 0; ks < 4; ++ks) {
            bf16x8 a[2];
            #pragma unroll
            for (int m = 0; m < 2; ++m) {
                const int r = m * 16 + l15;
                const int s = r & 7;
                const int cc = ks * 8 + lhi * 2;
                float4 q0 = *(const float4*)(buf + r * 128 + (((cc) ^ s) << 2));
                float4 q1 = *(const float4*)(buf + r * 128 + (((cc + 1) ^ s) << 2));
                union { unsigned u[4]; bf16x8 v; } pk;
                pk.u[0] = pack_bf16x2(q0.x, q0.y);
                pk.u[1] = pack_bf16x2(q0.z, q0.w);
                pk.u[2] = pack_bf16x2(q1.x, q1.y);
                pk.u[3] = pack_bf16x2(q1.z, q1.w);
                a[m] = pk.v;
            }
            #pragma unroll
            for (int n = 0; n < 2; ++n) {
                const int j16 = w * 2 + n;
                bf16x8 b = W1v[((j * 4 + ks) * 8 + j16) * 64 + l];
                #pragma unroll
                for (int m = 0; m < 2; ++m)
                    acc[m][n] = __builtin_amdgcn_mfma_f32_16x16x32_bf16(a[m], b, acc[m][n], 0, 0, 0);
            }
        }
    }
#undef ISSUE

    // bias + ReLU -> bf16 Hb aliased into smem[1] (chunk-3 buffer, all waves
    // done with it; concurrent chunk-4 readers use smem[0] — disjoint).
    unsigned short (*Hb)[D] = (unsigned short (*)[D])smem[1];
    #pragma unroll
    for (int n = 0; n < 2; ++n) {
        const int col = w * 32 + n * 16 + l15;
        const float bias = b1[col];
        #pragma unroll
        for (int m = 0; m < 2; ++m) {
            #pragma unroll
            for (int r = 0; r < 4; ++r) {
                float v = acc[m][n][r] + bias;
                v = v > 0.f ? v : 0.f;
                const int row = m * 16 + lhi * 4 + r;  // C/D: col=lane&15, row=(lane>>4)*4+reg
                Hb[row][col ^ ((row & 7) << 3)] = f32_to_bf16(v);
            }
        }
    }
    __syncthreads();

    // GEMM2: out = h @ W2^T  (M=32, N=32/wave, K=128)
    f32x4 acc2[2][2] = {};
    #pragma unroll
    for (int ks = 0; ks < 4; ++ks) {
        bf16x8 a2[2], bb[2];
        #pragma unroll
        for (int m = 0; m < 2; ++m) {
            const int row = m * 16 + l15;
            a2[m] = *(const bf16x8*)(&Hb[row][(ks * 32 + lhi * 8) ^ ((row & 7) << 3)]);
        }
        #pragma unroll
        for (int n = 0; n < 2; ++n) {
            const int j16 = w * 2 + n;
            bb[n] = W2v[(ks * 8 + j16) * 64 + l];
        }
        #pragma unroll
        for (int m = 0; m < 2; ++m)
            #pragma unroll
            for (int n = 0; n < 2; ++n)
                acc2[m][n] = __builtin_amdgcn_mfma_f32_16x16x32_bf16(a2[m], bb[n], acc2[m][n], 0, 0, 0);
    }

    // bias + fp32 store
    #pragma unroll
    for (int n = 0; n < 2; ++n) {
        const int col = w * 32 + n * 16 + l15;
        const float bias = b2[col];
        #pragma unroll
        for (int m = 0; m < 2; ++m) {
            #pragma unroll
            for (int r = 0; r < 4; ++r) {
                const int row = m * 16 + lhi * 4 + r;
                out[(size_t)(blk * BM + row) * D + col] = acc2[m][n][r] + bias;
            }
        }
    }
}

extern "C" void kernel_launch(void* const* d_in, const int* in_sizes, int n_in,
                              void* d_out, int out_size, void* d_ws, size_t ws_size,
                              hipStream_t stream) {
    const float* x_rows = (const float*)d_in[0];
    const int*   seeds  = (const int*)d_in[1];
    const float* W1     = (const float*)d_in[2];
    const float* b1     = (const float*)d_in[3];
    const float* W2     = (const float*)d_in[4];
    const float* b2     = (const float*)d_in[5];
    float* out = (float*)d_out;

    int Nrows = in_sizes[0] / D;
    int B = in_sizes[1];

    unsigned short* W1f = (unsigned short*)d_ws;
    unsigned short* W2f = W1f + W1F_ELEMS;

    prep_frags<<<(W1F_ELEMS + W2F_ELEMS + 255) / 256, 256, 0, stream>>>(W1, W2, W1f, W2f);
    rowmlp_kernel<<<B / BM, 256, 0, stream>>>(x_rows, seeds, W1f, b1, W2f, b2, out, Nrows);
}